// Round 1
// baseline (170.420 us; speedup 1.0000x reference)
//
#include <hip/hip_runtime.h>

#define SDIM 65536
#define BDIM 32
#define RDIM 128
#define NDEG 4
#define NCHUNK 256
#define CHUNK_S (SDIM / NCHUNK)   /* 256 s-values per chunk */
#define MTOT (BDIM * SDIM)        /* 2097152 */
#define EPS_BN 1e-5f

// ---------------- K1: batch stats (sum, sumsq) ----------------
__global__ void k_stats(const float* __restrict__ x, float* __restrict__ stats) {
    __shared__ float s_sum[256];
    __shared__ float s_sq[256];
    int tid = threadIdx.x;
    int gid = blockIdx.x * 256 + tid;
    int stride = gridDim.x * 256;
    float sum = 0.f, sq = 0.f;
    const float4* x4 = (const float4*)x;
    for (int i = gid; i < MTOT / 4; i += stride) {
        float4 v = x4[i];
        sum += (v.x + v.y) + (v.z + v.w);
        sq  += (v.x * v.x + v.y * v.y) + (v.z * v.z + v.w * v.w);
    }
    s_sum[tid] = sum; s_sq[tid] = sq;
    __syncthreads();
    for (int off = 128; off > 0; off >>= 1) {
        if (tid < off) { s_sum[tid] += s_sum[tid + off]; s_sq[tid] += s_sq[tid + off]; }
        __syncthreads();
    }
    if (tid == 0) { atomicAdd(&stats[0], s_sum[0]); atomicAdd(&stats[1], s_sq[0]); }
}

// ---------------- K2: normalize + transpose -> zT[s][b] ----------------
__global__ void k_norm_t(const float* __restrict__ x, const float* __restrict__ gamma,
                         const float* __restrict__ bnb, const float* __restrict__ stats,
                         float* __restrict__ zT) {
    int s = blockIdx.x * 256 + threadIdx.x;
    float mean = stats[0] * (1.f / MTOT);
    float var  = stats[1] * (1.f / MTOT) - mean * mean;
    float istd = rsqrtf(var + EPS_BN);
    float a  = gamma[0] * istd;
    float c0 = bnb[0] - mean * a;
#pragma unroll
    for (int b = 0; b < BDIM; ++b) {
        zT[s * BDIM + b] = fmaf(a, x[(size_t)b * SDIM + s], c0);
    }
}

// ---------------- K3: t_part[n][chunk][b][r] = sum_{s in chunk} zT[s][b] * U[n][s][r] ----
__global__ void __launch_bounds__(256) k_gemm_t(const float* __restrict__ zT,
                                                const float* __restrict__ U,
                                                float* __restrict__ t_part) {
    __shared__ float lds[2 * BDIM * RDIM];  // 32 KB
    int tid  = threadIdx.x;
    int r    = tid & 127;
    // force wave-uniform so zT addresses scalarize to s_load
    int half = __builtin_amdgcn_readfirstlane(tid >> 7);
    int chunk = blockIdx.x;   // 0..NCHUNK-1
    int n     = blockIdx.y;   // 0..NDEG-1
    int s0 = chunk * CHUNK_S + half * (CHUNK_S / 2);

    const float* Ub = U + (size_t)n * SDIM * RDIM;
    float acc[BDIM];
#pragma unroll
    for (int b = 0; b < BDIM; ++b) acc[b] = 0.f;

#pragma unroll 2
    for (int s = s0; s < s0 + CHUNK_S / 2; ++s) {
        float u = Ub[(size_t)s * RDIM + r];
        const float* zr = zT + (size_t)s * BDIM;   // wave-uniform row
#pragma unroll
        for (int b = 0; b < BDIM; ++b)
            acc[b] = fmaf(zr[b], u, acc[b]);
    }

#pragma unroll
    for (int b = 0; b < BDIM; ++b)
        lds[half * (BDIM * RDIM) + b * RDIM + r] = acc[b];
    __syncthreads();

    float* outp = t_part + (size_t)(n * NCHUNK + chunk) * (BDIM * RDIM);
    for (int i = tid; i < BDIM * RDIM; i += 256)
        outp[i] = lds[i] + lds[BDIM * RDIM + i];
}

// ---------------- K4: reduce partials over chunks + Horner -> h[b][r] ----------------
__global__ void k_reduce_h(const float* __restrict__ t_part, float* __restrict__ h) {
    int i = blockIdx.x * 256 + threadIdx.x;  // 0..4095 = b*128+r
    float t[NDEG];
#pragma unroll
    for (int n = 0; n < NDEG; ++n) {
        float s = 0.f;
        for (int c = 0; c < NCHUNK; ++c)
            s += t_part[(size_t)(n * NCHUNK + c) * (BDIM * RDIM) + i];
        t[n] = s;
    }
    float hh = t[0];
#pragma unroll
    for (int n = 1; n < NDEG; ++n) hh = fmaf(t[n], hh, hh);
    h[i] = hh;
}

// ---------------- K5: out[b][s] = beta[s] + sum_r h[b][r]*C[s][r] ----------------
__global__ void __launch_bounds__(256) k_out(const float* __restrict__ h,
                                             const float* __restrict__ Cm,
                                             const float* __restrict__ beta,
                                             float* __restrict__ out) {
    int s = blockIdx.x * 256 + threadIdx.x;
    float acc[BDIM];
#pragma unroll
    for (int b = 0; b < BDIM; ++b) acc[b] = 0.f;
    const float4* Cr = (const float4*)(Cm + (size_t)s * RDIM);
    for (int rc = 0; rc < RDIM / 16; ++rc) {
        float4 c0 = Cr[rc * 4 + 0];
        float4 c1 = Cr[rc * 4 + 1];
        float4 c2 = Cr[rc * 4 + 2];
        float4 c3 = Cr[rc * 4 + 3];
#pragma unroll
        for (int b = 0; b < BDIM; ++b) {
            const float* hb = h + b * RDIM + rc * 16;   // wave-uniform -> s_load
            float a = acc[b];
            a = fmaf(c0.x, hb[0],  a);  a = fmaf(c0.y, hb[1],  a);
            a = fmaf(c0.z, hb[2],  a);  a = fmaf(c0.w, hb[3],  a);
            a = fmaf(c1.x, hb[4],  a);  a = fmaf(c1.y, hb[5],  a);
            a = fmaf(c1.z, hb[6],  a);  a = fmaf(c1.w, hb[7],  a);
            a = fmaf(c2.x, hb[8],  a);  a = fmaf(c2.y, hb[9],  a);
            a = fmaf(c2.z, hb[10], a);  a = fmaf(c2.w, hb[11], a);
            a = fmaf(c3.x, hb[12], a);  a = fmaf(c3.y, hb[13], a);
            a = fmaf(c3.z, hb[14], a);  a = fmaf(c3.w, hb[15], a);
            acc[b] = a;
        }
    }
    float bt = beta[s];
#pragma unroll
    for (int b = 0; b < BDIM; ++b)
        out[(size_t)b * SDIM + s] = acc[b] + bt;
}

extern "C" void kernel_launch(void* const* d_in, const int* in_sizes, int n_in,
                              void* d_out, int out_size, void* d_ws, size_t ws_size,
                              hipStream_t stream) {
    const float* x     = (const float*)d_in[0];
    const float* U     = (const float*)d_in[1];
    const float* Cm    = (const float*)d_in[2];
    const float* beta  = (const float*)d_in[3];
    const float* gamma = (const float*)d_in[4];
    const float* bnb   = (const float*)d_in[5];
    float* out = (float*)d_out;

    char* ws = (char*)d_ws;
    float* stats  = (float*)ws;                                   // 2 floats
    float* zT     = (float*)(ws + 256);                           // 32*65536 f32 = 8 MB
    float* t_part = (float*)(ws + 256 + (size_t)BDIM * SDIM * 4); // 4*256*4096 f32 = 16 MB
    float* h      = (float*)(ws + 256 + (size_t)BDIM * SDIM * 4
                                  + (size_t)NDEG * NCHUNK * BDIM * RDIM * 4); // 4096 f32

    hipMemsetAsync(stats, 0, 8, stream);
    k_stats<<<512, 256, 0, stream>>>(x, stats);
    k_norm_t<<<SDIM / 256, 256, 0, stream>>>(x, gamma, bnb, stats, zT);
    dim3 g3(NCHUNK, NDEG);
    k_gemm_t<<<g3, 256, 0, stream>>>(zT, U, t_part);
    k_reduce_h<<<16, 256, 0, stream>>>(t_part, h);
    k_out<<<SDIM / 256, 256, 0, stream>>>(h, Cm, beta, out);
}

// Round 2
// 147.635 us; speedup vs baseline: 1.1543x; 1.1543x over previous
//
#include <hip/hip_runtime.h>

#define SDIM 65536
#define BDIM 32
#define RDIM 128
#define NDEG 4
#define NCHUNK 256
#define CHUNK_S (SDIM / NCHUNK)   /* 256 s-values per chunk */
#define MTOT (BDIM * SDIM)        /* 2097152 */
#define EPS_BN 1e-5f

// ---------------- K1: batch stats (sum, sumsq) ----------------
__global__ void k_stats(const float* __restrict__ x, float* __restrict__ stats) {
    __shared__ float s_sum[256];
    __shared__ float s_sq[256];
    int tid = threadIdx.x;
    int gid = blockIdx.x * 256 + tid;
    int stride = gridDim.x * 256;
    float sum = 0.f, sq = 0.f;
    const float4* x4 = (const float4*)x;
    for (int i = gid; i < MTOT / 4; i += stride) {
        float4 v = x4[i];
        sum += (v.x + v.y) + (v.z + v.w);
        sq  += (v.x * v.x + v.y * v.y) + (v.z * v.z + v.w * v.w);
    }
    s_sum[tid] = sum; s_sq[tid] = sq;
    __syncthreads();
    for (int off = 128; off > 0; off >>= 1) {
        if (tid < off) { s_sum[tid] += s_sum[tid + off]; s_sq[tid] += s_sq[tid + off]; }
        __syncthreads();
    }
    if (tid == 0) { atomicAdd(&stats[0], s_sum[0]); atomicAdd(&stats[1], s_sq[0]); }
}

// ---------------- K2: normalize + transpose -> zT[s][b], LDS tiled ----------------
__global__ void __launch_bounds__(256) k_norm_t(const float* __restrict__ x,
                                                const float* __restrict__ gamma,
                                                const float* __restrict__ bnb,
                                                const float* __restrict__ stats,
                                                float* __restrict__ zT) {
    __shared__ float lds[64][33];   // pad to kill bank conflicts
    int tid = threadIdx.x;
    int s0 = blockIdx.x * 64;
    float mean = stats[0] * (1.f / MTOT);
    float var  = stats[1] * (1.f / MTOT) - mean * mean;
    float istd = rsqrtf(var + EPS_BN);
    float a  = gamma[0] * istd;
    float c0 = bnb[0] - mean * a;

    int sl = tid & 63, bq = tid >> 6;     // load phase: lane along s (coalesced)
#pragma unroll
    for (int k = 0; k < 8; ++k) {
        int b = k * 4 + bq;
        lds[sl][b] = fmaf(a, x[(size_t)b * SDIM + s0 + sl], c0);
    }
    __syncthreads();
    int bl = tid & 31, sq = tid >> 5;     // store phase: lane along b (coalesced)
#pragma unroll
    for (int k = 0; k < 8; ++k) {
        int s = k * 8 + sq;
        zT[(size_t)(s0 + s) * BDIM + bl] = lds[s][bl];
    }
}

// ---------------- K3: t_part[n][chunk][b][r] = sum_{s in chunk} zT[s][b] * U[n][s][r] ----
__global__ void __launch_bounds__(256) k_gemm_t(const float* __restrict__ zT,
                                                const float* __restrict__ U,
                                                float* __restrict__ t_part) {
    __shared__ float lds[2 * BDIM * RDIM];  // 32 KB
    int tid  = threadIdx.x;
    int r    = tid & 127;
    int half = __builtin_amdgcn_readfirstlane(tid >> 7);
    int chunk = blockIdx.x;   // 0..NCHUNK-1
    int n     = blockIdx.y;   // 0..NDEG-1
    int s0 = chunk * CHUNK_S + half * (CHUNK_S / 2);

    const float* Ub = U + (size_t)n * SDIM * RDIM;
    float acc[BDIM];
#pragma unroll
    for (int b = 0; b < BDIM; ++b) acc[b] = 0.f;

#pragma unroll 2
    for (int s = s0; s < s0 + CHUNK_S / 2; ++s) {
        float u = Ub[(size_t)s * RDIM + r];
        const float* zr = zT + (size_t)s * BDIM;   // wave-uniform row -> s_load
#pragma unroll
        for (int b = 0; b < BDIM; ++b)
            acc[b] = fmaf(zr[b], u, acc[b]);
    }

#pragma unroll
    for (int b = 0; b < BDIM; ++b)
        lds[half * (BDIM * RDIM) + b * RDIM + r] = acc[b];
    __syncthreads();

    float* outp = t_part + (size_t)(n * NCHUNK + chunk) * (BDIM * RDIM);
    for (int i = tid; i < BDIM * RDIM; i += 256)
        outp[i] = lds[i] + lds[BDIM * RDIM + i];
}

// ---------------- K4a: partial reduce over 16-chunk groups ----------------
__global__ void k_reduce_a(const float* __restrict__ t_part, float* __restrict__ t_mid) {
    int i  = blockIdx.x * 256 + threadIdx.x;  // 0..4095 (b*128+r)
    int cg = blockIdx.y;                      // 0..15
    int n  = blockIdx.z;                      // 0..3
    float s = 0.f;
#pragma unroll
    for (int c = cg * 16; c < cg * 16 + 16; ++c)
        s += t_part[(size_t)(n * NCHUNK + c) * (BDIM * RDIM) + i];
    t_mid[((size_t)n * 16 + cg) * (BDIM * RDIM) + i] = s;
}

// ---------------- K4b: final reduce + Horner -> h[b][r] ----------------
__global__ void k_reduce_b(const float* __restrict__ t_mid, float* __restrict__ h) {
    int i = blockIdx.x * 64 + threadIdx.x;    // 0..4095
    float t[NDEG];
#pragma unroll
    for (int n = 0; n < NDEG; ++n) {
        float s = 0.f;
#pragma unroll
        for (int cg = 0; cg < 16; ++cg)
            s += t_mid[((size_t)n * 16 + cg) * (BDIM * RDIM) + i];
        t[n] = s;
    }
    float hh = t[0];
#pragma unroll
    for (int n = 1; n < NDEG; ++n) hh = fmaf(t[n], hh, hh);
    h[i] = hh;
}

// ---------------- K5: out[b][s] = beta[s] + sum_r h[b][r]*C[s][r], 8-way b-split ----
__global__ void __launch_bounds__(256) k_out(const float* __restrict__ h,
                                             const float* __restrict__ Cm,
                                             const float* __restrict__ beta,
                                             float* __restrict__ out) {
    int tid = threadIdx.x;
    int s   = (blockIdx.x >> 1) * 64 + (tid & 63);
    int bg  = (blockIdx.x & 1) * 4 + (tid >> 6);   // wave-uniform b-group 0..7
    int b0  = bg * 4;

    float acc[4] = {0.f, 0.f, 0.f, 0.f};
    const float4* Cr = (const float4*)(Cm + (size_t)s * RDIM);
    const float* hb = h + b0 * RDIM;               // wave-uniform base -> s_load

#pragma unroll 8
    for (int rc = 0; rc < RDIM / 4; ++rc) {
        float4 c = Cr[rc];
#pragma unroll
        for (int j = 0; j < 4; ++j) {
            const float* hr = hb + j * RDIM + rc * 4;
            float a = acc[j];
            a = fmaf(c.x, hr[0], a);
            a = fmaf(c.y, hr[1], a);
            a = fmaf(c.z, hr[2], a);
            a = fmaf(c.w, hr[3], a);
            acc[j] = a;
        }
    }
    float bt = beta[s];
#pragma unroll
    for (int j = 0; j < 4; ++j)
        out[(size_t)(b0 + j) * SDIM + s] = acc[j] + bt;
}

extern "C" void kernel_launch(void* const* d_in, const int* in_sizes, int n_in,
                              void* d_out, int out_size, void* d_ws, size_t ws_size,
                              hipStream_t stream) {
    const float* x     = (const float*)d_in[0];
    const float* U     = (const float*)d_in[1];
    const float* Cm    = (const float*)d_in[2];
    const float* beta  = (const float*)d_in[3];
    const float* gamma = (const float*)d_in[4];
    const float* bnb   = (const float*)d_in[5];
    float* out = (float*)d_out;

    char* ws = (char*)d_ws;
    size_t off = 0;
    float* stats  = (float*)(ws + off); off += 256;
    float* zT     = (float*)(ws + off); off += (size_t)BDIM * SDIM * 4;            // 8 MB
    float* t_part = (float*)(ws + off); off += (size_t)NDEG * NCHUNK * BDIM * RDIM * 4; // 16 MB
    float* t_mid  = (float*)(ws + off); off += (size_t)NDEG * 16 * BDIM * RDIM * 4;     // 1 MB
    float* h      = (float*)(ws + off); off += (size_t)BDIM * RDIM * 4;            // 16 KB

    hipMemsetAsync(stats, 0, 8, stream);
    k_stats<<<512, 256, 0, stream>>>(x, stats);
    k_norm_t<<<SDIM / 64, 256, 0, stream>>>(x, gamma, bnb, stats, zT);
    dim3 g3(NCHUNK, NDEG);
    k_gemm_t<<<g3, 256, 0, stream>>>(zT, U, t_part);
    dim3 g4(16, 16, NDEG);
    k_reduce_a<<<g4, 256, 0, stream>>>(t_part, t_mid);
    k_reduce_b<<<64, 64, 0, stream>>>(t_mid, h);
    k_out<<<2048, 256, 0, stream>>>(h, Cm, beta, out);
}

// Round 3
// 132.342 us; speedup vs baseline: 1.2877x; 1.1156x over previous
//
#include <hip/hip_runtime.h>

#define SDIM 65536
#define BDIM 32
#define RDIM 128
#define NDEG 4
#define NCHUNK 256
#define CHUNK_S (SDIM / NCHUNK)   /* 256 s-values per chunk */
#define MTOT (BDIM * SDIM)        /* 2097152 */
#define EPS_BN 1e-5f
#define NSTATB 512                /* k_stats grid */

// ---------------- K1a: per-block partial stats (no atomics, no init needed) ----
__global__ void k_stats(const float* __restrict__ x, float* __restrict__ partial) {
    __shared__ float s_sum[256];
    __shared__ float s_sq[256];
    int tid = threadIdx.x;
    int gid = blockIdx.x * 256 + tid;
    int stride = gridDim.x * 256;
    float sum = 0.f, sq = 0.f;
    const float4* x4 = (const float4*)x;
    for (int i = gid; i < MTOT / 4; i += stride) {
        float4 v = x4[i];
        sum += (v.x + v.y) + (v.z + v.w);
        sq  += (v.x * v.x + v.y * v.y) + (v.z * v.z + v.w * v.w);
    }
    s_sum[tid] = sum; s_sq[tid] = sq;
    __syncthreads();
    for (int off = 128; off > 0; off >>= 1) {
        if (tid < off) { s_sum[tid] += s_sum[tid + off]; s_sq[tid] += s_sq[tid + off]; }
        __syncthreads();
    }
    if (tid == 0) { partial[blockIdx.x * 2] = s_sum[0]; partial[blockIdx.x * 2 + 1] = s_sq[0]; }
}

// ---------------- K1b: finalize stats (1 block) ----------------
__global__ void k_stats_fin(const float* __restrict__ partial, float* __restrict__ stats) {
    __shared__ float s_sum[256];
    __shared__ float s_sq[256];
    int tid = threadIdx.x;
    float sum = partial[tid * 2] + partial[(tid + 256) * 2];
    float sq  = partial[tid * 2 + 1] + partial[(tid + 256) * 2 + 1];
    s_sum[tid] = sum; s_sq[tid] = sq;
    __syncthreads();
    for (int off = 128; off > 0; off >>= 1) {
        if (tid < off) { s_sum[tid] += s_sum[tid + off]; s_sq[tid] += s_sq[tid + off]; }
        __syncthreads();
    }
    if (tid == 0) { stats[0] = s_sum[0]; stats[1] = s_sq[0]; }
}

// ---------------- K2: normalize + transpose -> zT[s][b], LDS tiled ----------------
__global__ void __launch_bounds__(256) k_norm_t(const float* __restrict__ x,
                                                const float* __restrict__ gamma,
                                                const float* __restrict__ bnb,
                                                const float* __restrict__ stats,
                                                float* __restrict__ zT) {
    __shared__ float lds[64][33];   // pad to kill bank conflicts
    int tid = threadIdx.x;
    int s0 = blockIdx.x * 64;
    float mean = stats[0] * (1.f / MTOT);
    float var  = stats[1] * (1.f / MTOT) - mean * mean;
    float istd = rsqrtf(var + EPS_BN);
    float a  = gamma[0] * istd;
    float c0 = bnb[0] - mean * a;

    int sl = tid & 63, bq = tid >> 6;     // load phase: lane along s (coalesced)
#pragma unroll
    for (int k = 0; k < 8; ++k) {
        int b = k * 4 + bq;
        lds[sl][b] = fmaf(a, x[(size_t)b * SDIM + s0 + sl], c0);
    }
    __syncthreads();
    int bl = tid & 31, sq = tid >> 5;     // store phase: lane along b (coalesced)
#pragma unroll
    for (int k = 0; k < 8; ++k) {
        int s = k * 8 + sq;
        zT[(size_t)(s0 + s) * BDIM + bl] = lds[s][bl];
    }
}

// ---------------- K3: t_part[n][chunk][b][r] = sum_{s in chunk} zT[s][b] * U[n][s][r] ----
__global__ void __launch_bounds__(256) k_gemm_t(const float* __restrict__ zT,
                                                const float* __restrict__ U,
                                                float* __restrict__ t_part) {
    __shared__ float lds[2 * BDIM * RDIM];  // 32 KB
    int tid  = threadIdx.x;
    int r    = tid & 127;
    int half = __builtin_amdgcn_readfirstlane(tid >> 7);
    int chunk = blockIdx.x;   // 0..NCHUNK-1
    int n     = blockIdx.y;   // 0..NDEG-1
    int s0 = chunk * CHUNK_S + half * (CHUNK_S / 2);

    const float* Ub = U + (size_t)n * SDIM * RDIM;
    float acc[BDIM];
#pragma unroll
    for (int b = 0; b < BDIM; ++b) acc[b] = 0.f;

#pragma unroll 2
    for (int s = s0; s < s0 + CHUNK_S / 2; ++s) {
        float u = Ub[(size_t)s * RDIM + r];
        const float* zr = zT + (size_t)s * BDIM;   // wave-uniform row -> s_load
#pragma unroll
        for (int b = 0; b < BDIM; ++b)
            acc[b] = fmaf(zr[b], u, acc[b]);
    }

#pragma unroll
    for (int b = 0; b < BDIM; ++b)
        lds[half * (BDIM * RDIM) + b * RDIM + r] = acc[b];
    __syncthreads();

    float* outp = t_part + (size_t)(n * NCHUNK + chunk) * (BDIM * RDIM);
    for (int i = tid; i < BDIM * RDIM; i += 256)
        outp[i] = lds[i] + lds[BDIM * RDIM + i];
}

// ---------------- K4a: partial reduce over 16-chunk groups ----------------
__global__ void k_reduce_a(const float* __restrict__ t_part, float* __restrict__ t_mid) {
    int i  = blockIdx.x * 256 + threadIdx.x;  // 0..4095 (b*128+r)
    int cg = blockIdx.y;                      // 0..15
    int n  = blockIdx.z;                      // 0..3
    float s = 0.f;
#pragma unroll
    for (int c = cg * 16; c < cg * 16 + 16; ++c)
        s += t_part[(size_t)(n * NCHUNK + c) * (BDIM * RDIM) + i];
    t_mid[((size_t)n * 16 + cg) * (BDIM * RDIM) + i] = s;
}

// ---------------- K4b: final reduce + Horner -> h[b][r] ----------------
__global__ void k_reduce_b(const float* __restrict__ t_mid, float* __restrict__ h) {
    int i = blockIdx.x * 64 + threadIdx.x;    // 0..4095
    float t[NDEG];
#pragma unroll
    for (int n = 0; n < NDEG; ++n) {
        float s = 0.f;
#pragma unroll
        for (int cg = 0; cg < 16; ++cg)
            s += t_mid[((size_t)n * 16 + cg) * (BDIM * RDIM) + i];
        t[n] = s;
    }
    float hh = t[0];
#pragma unroll
    for (int n = 1; n < NDEG; ++n) hh = fmaf(t[n], hh, hh);
    h[i] = hh;
}

// ---------------- K5: out[b][s] = beta[s] + sum_r h[b][r]*C[s][r], 8-way b-split ----
__global__ void __launch_bounds__(256) k_out(const float* __restrict__ h,
                                             const float* __restrict__ Cm,
                                             const float* __restrict__ beta,
                                             float* __restrict__ out) {
    int tid = threadIdx.x;
    int s   = (blockIdx.x >> 1) * 64 + (tid & 63);
    int bg  = (blockIdx.x & 1) * 4 + (tid >> 6);   // wave-uniform b-group 0..7
    int b0  = bg * 4;

    float acc[4] = {0.f, 0.f, 0.f, 0.f};
    const float4* Cr = (const float4*)(Cm + (size_t)s * RDIM);
    const float* hb = h + b0 * RDIM;               // wave-uniform base -> s_load

#pragma unroll 8
    for (int rc = 0; rc < RDIM / 4; ++rc) {
        float4 c = Cr[rc];
#pragma unroll
        for (int j = 0; j < 4; ++j) {
            const float* hr = hb + j * RDIM + rc * 4;
            float a = acc[j];
            a = fmaf(c.x, hr[0], a);
            a = fmaf(c.y, hr[1], a);
            a = fmaf(c.z, hr[2], a);
            a = fmaf(c.w, hr[3], a);
            acc[j] = a;
        }
    }
    float bt = beta[s];
#pragma unroll
    for (int j = 0; j < 4; ++j)
        out[(size_t)(b0 + j) * SDIM + s] = acc[j] + bt;
}

extern "C" void kernel_launch(void* const* d_in, const int* in_sizes, int n_in,
                              void* d_out, int out_size, void* d_ws, size_t ws_size,
                              hipStream_t stream) {
    const float* x     = (const float*)d_in[0];
    const float* U     = (const float*)d_in[1];
    const float* Cm    = (const float*)d_in[2];
    const float* beta  = (const float*)d_in[3];
    const float* gamma = (const float*)d_in[4];
    const float* bnb   = (const float*)d_in[5];
    float* out = (float*)d_out;

    char* ws = (char*)d_ws;
    size_t off = 0;
    float* stats   = (float*)(ws + off); off += 256;
    float* partial = (float*)(ws + off); off += NSTATB * 2 * 4;
    float* zT      = (float*)(ws + off); off += (size_t)BDIM * SDIM * 4;            // 8 MB
    float* t_part  = (float*)(ws + off); off += (size_t)NDEG * NCHUNK * BDIM * RDIM * 4; // 16 MB
    float* t_mid   = (float*)(ws + off); off += (size_t)NDEG * 16 * BDIM * RDIM * 4;     // 1 MB
    float* h       = (float*)(ws + off); off += (size_t)BDIM * RDIM * 4;            // 16 KB

    k_stats<<<NSTATB, 256, 0, stream>>>(x, partial);
    k_stats_fin<<<1, 256, 0, stream>>>(partial, stats);
    k_norm_t<<<SDIM / 64, 256, 0, stream>>>(x, gamma, bnb, stats, zT);
    dim3 g3(NCHUNK, NDEG);
    k_gemm_t<<<g3, 256, 0, stream>>>(zT, U, t_part);
    dim3 g4(16, 16, NDEG);
    k_reduce_a<<<g4, 256, 0, stream>>>(t_part, t_mid);
    k_reduce_b<<<64, 64, 0, stream>>>(t_mid, h);
    k_out<<<2048, 256, 0, stream>>>(h, Cm, beta, out);
}

// Round 4
// 99.258 us; speedup vs baseline: 1.7169x; 1.3333x over previous
//
#include <hip/hip_runtime.h>

#define SDIM 65536
#define BDIM 32
#define RDIM 128
#define NDEG 4
#define NCHUNK 256
#define CHUNK_S (SDIM / NCHUNK)   /* 256 s-values per chunk */
#define MTOT (BDIM * SDIM)        /* 2097152 */
#define EPS_BN 1e-5f
#define NSTATB 512                /* k_stats grid */

// ---------------- K1a: per-block partial stats (no atomics, no init needed) ----
__global__ void k_stats(const float* __restrict__ x, float* __restrict__ partial) {
    __shared__ float s_sum[256];
    __shared__ float s_sq[256];
    int tid = threadIdx.x;
    int gid = blockIdx.x * 256 + tid;
    int stride = gridDim.x * 256;
    float sum = 0.f, sq = 0.f;
    const float4* x4 = (const float4*)x;
    for (int i = gid; i < MTOT / 4; i += stride) {
        float4 v = x4[i];
        sum += (v.x + v.y) + (v.z + v.w);
        sq  += (v.x * v.x + v.y * v.y) + (v.z * v.z + v.w * v.w);
    }
    s_sum[tid] = sum; s_sq[tid] = sq;
    __syncthreads();
    for (int off = 128; off > 0; off >>= 1) {
        if (tid < off) { s_sum[tid] += s_sum[tid + off]; s_sq[tid] += s_sq[tid + off]; }
        __syncthreads();
    }
    if (tid == 0) { partial[blockIdx.x * 2] = s_sum[0]; partial[blockIdx.x * 2 + 1] = s_sq[0]; }
}

// ---------------- K1b: finalize stats (1 block) ----------------
__global__ void k_stats_fin(const float* __restrict__ partial, float* __restrict__ stats) {
    __shared__ float s_sum[256];
    __shared__ float s_sq[256];
    int tid = threadIdx.x;
    float sum = partial[tid * 2] + partial[(tid + 256) * 2];
    float sq  = partial[tid * 2 + 1] + partial[(tid + 256) * 2 + 1];
    s_sum[tid] = sum; s_sq[tid] = sq;
    __syncthreads();
    for (int off = 128; off > 0; off >>= 1) {
        if (tid < off) { s_sum[tid] += s_sum[tid + off]; s_sq[tid] += s_sq[tid + off]; }
        __syncthreads();
    }
    if (tid == 0) { stats[0] = s_sum[0]; stats[1] = s_sq[0]; }
}

// ---------------- K2: normalize + transpose -> zT[s][b], LDS tiled ----------------
__global__ void __launch_bounds__(256) k_norm_t(const float* __restrict__ x,
                                                const float* __restrict__ gamma,
                                                const float* __restrict__ bnb,
                                                const float* __restrict__ stats,
                                                float* __restrict__ zT) {
    __shared__ float lds[64][33];   // pad to kill bank conflicts
    int tid = threadIdx.x;
    int s0 = blockIdx.x * 64;
    float mean = stats[0] * (1.f / MTOT);
    float var  = stats[1] * (1.f / MTOT) - mean * mean;
    float istd = rsqrtf(var + EPS_BN);
    float a  = gamma[0] * istd;
    float c0 = bnb[0] - mean * a;

    int sl = tid & 63, bq = tid >> 6;     // load phase: lane along s (coalesced)
#pragma unroll
    for (int k = 0; k < 8; ++k) {
        int b = k * 4 + bq;
        lds[sl][b] = fmaf(a, x[(size_t)b * SDIM + s0 + sl], c0);
    }
    __syncthreads();
    int bl = tid & 31, sq = tid >> 5;     // store phase: lane along b (coalesced)
#pragma unroll
    for (int k = 0; k < 8; ++k) {
        int s = k * 8 + sq;
        zT[(size_t)(s0 + s) * BDIM + bl] = lds[s][bl];
    }
}

// ---------------- K3: t_part[n][chunk][b][r] = sum_{s in chunk} zT[s][b] * U[n][s][r] ----
__global__ void __launch_bounds__(256) k_gemm_t(const float* __restrict__ zT,
                                                const float* __restrict__ U,
                                                float* __restrict__ t_part) {
    __shared__ float lds[2 * BDIM * RDIM];  // 32 KB
    int tid  = threadIdx.x;
    int r    = tid & 127;
    int half = __builtin_amdgcn_readfirstlane(tid >> 7);
    int chunk = blockIdx.x;   // 0..NCHUNK-1
    int n     = blockIdx.y;   // 0..NDEG-1
    int s0 = chunk * CHUNK_S + half * (CHUNK_S / 2);

    const float* Ub = U + (size_t)n * SDIM * RDIM;
    float acc[BDIM];
#pragma unroll
    for (int b = 0; b < BDIM; ++b) acc[b] = 0.f;

#pragma unroll 2
    for (int s = s0; s < s0 + CHUNK_S / 2; ++s) {
        float u = Ub[(size_t)s * RDIM + r];
        const float* zr = zT + (size_t)s * BDIM;   // wave-uniform row -> s_load
#pragma unroll
        for (int b = 0; b < BDIM; ++b)
            acc[b] = fmaf(zr[b], u, acc[b]);
    }

#pragma unroll
    for (int b = 0; b < BDIM; ++b)
        lds[half * (BDIM * RDIM) + b * RDIM + r] = acc[b];
    __syncthreads();

    float* outp = t_part + (size_t)(n * NCHUNK + chunk) * (BDIM * RDIM);
    for (int i = tid; i < BDIM * RDIM; i += 256)
        outp[i] = lds[i] + lds[BDIM * RDIM + i];
}

// ---------------- K4: fused reduce over 256 chunks + Horner -> h[b][r] ----------------
// block: 256 thr = 8 chunk-groups x 32 i-lanes; grid: 128 blocks (32 i each)
__global__ void __launch_bounds__(256) k_reduce_h(const float* __restrict__ t_part,
                                                  float* __restrict__ h) {
    __shared__ float lds[NDEG][8][32];
    int tid = threadIdx.x;
    int il = tid & 31;        // i-lane within block's 32-wide i-slice
    int cg = tid >> 5;        // chunk group 0..7 (32 chunks each)
    int i0 = blockIdx.x * 32;

#pragma unroll
    for (int n = 0; n < NDEG; ++n) {
        float s = 0.f;
#pragma unroll 4
        for (int k = 0; k < 32; ++k) {
            int c = cg * 32 + k;
            s += t_part[(size_t)(n * NCHUNK + c) * (BDIM * RDIM) + i0 + il];
        }
        lds[n][cg][il] = s;
    }
    __syncthreads();
    if (tid < 32) {
        float t[NDEG];
#pragma unroll
        for (int n = 0; n < NDEG; ++n) {
            float s = 0.f;
#pragma unroll
            for (int g = 0; g < 8; ++g) s += lds[n][g][il];
            t[n] = s;
        }
        float hh = t[0];
#pragma unroll
        for (int n = 1; n < NDEG; ++n) hh = fmaf(t[n], hh, hh);
        h[i0 + il] = hh;
    }
}

// ---------------- K5: out[b][s] = beta[s] + sum_r h[b][r]*C[s][r], 8-way b-split ----
__global__ void __launch_bounds__(256) k_out(const float* __restrict__ h,
                                             const float* __restrict__ Cm,
                                             const float* __restrict__ beta,
                                             float* __restrict__ out) {
    int tid = threadIdx.x;
    int s   = (blockIdx.x >> 1) * 64 + (tid & 63);
    // wave-uniform b-group: force scalarization so h reads become s_load
    int bg  = __builtin_amdgcn_readfirstlane((blockIdx.x & 1) * 4 + (tid >> 6));
    int b0  = bg * 4;

    float acc[4] = {0.f, 0.f, 0.f, 0.f};
    const float4* Cr = (const float4*)(Cm + (size_t)s * RDIM);
    const float* hb = h + b0 * RDIM;               // wave-uniform base -> s_load

#pragma unroll 8
    for (int rc = 0; rc < RDIM / 4; ++rc) {
        float4 c = Cr[rc];
#pragma unroll
        for (int j = 0; j < 4; ++j) {
            const float* hr = hb + j * RDIM + rc * 4;
            float a = acc[j];
            a = fmaf(c.x, hr[0], a);
            a = fmaf(c.y, hr[1], a);
            a = fmaf(c.z, hr[2], a);
            a = fmaf(c.w, hr[3], a);
            acc[j] = a;
        }
    }
    float bt = beta[s];
#pragma unroll
    for (int j = 0; j < 4; ++j)
        out[(size_t)(b0 + j) * SDIM + s] = acc[j] + bt;
}

extern "C" void kernel_launch(void* const* d_in, const int* in_sizes, int n_in,
                              void* d_out, int out_size, void* d_ws, size_t ws_size,
                              hipStream_t stream) {
    const float* x     = (const float*)d_in[0];
    const float* U     = (const float*)d_in[1];
    const float* Cm    = (const float*)d_in[2];
    const float* beta  = (const float*)d_in[3];
    const float* gamma = (const float*)d_in[4];
    const float* bnb   = (const float*)d_in[5];
    float* out = (float*)d_out;

    char* ws = (char*)d_ws;
    size_t off = 0;
    float* stats   = (float*)(ws + off); off += 256;
    float* partial = (float*)(ws + off); off += NSTATB * 2 * 4;
    float* zT      = (float*)(ws + off); off += (size_t)BDIM * SDIM * 4;            // 8 MB
    float* t_part  = (float*)(ws + off); off += (size_t)NDEG * NCHUNK * BDIM * RDIM * 4; // 16 MB
    float* h       = (float*)(ws + off); off += (size_t)BDIM * RDIM * 4;            // 16 KB

    k_stats<<<NSTATB, 256, 0, stream>>>(x, partial);
    k_stats_fin<<<1, 256, 0, stream>>>(partial, stats);
    k_norm_t<<<SDIM / 64, 256, 0, stream>>>(x, gamma, bnb, stats, zT);
    dim3 g3(NCHUNK, NDEG);
    k_gemm_t<<<g3, 256, 0, stream>>>(zT, U, t_part);
    k_reduce_h<<<128, 256, 0, stream>>>(t_part, h);
    k_out<<<2048, 256, 0, stream>>>(h, Cm, beta, out);
}